// Round 12
// baseline (95.389 us; speedup 1.0000x reference)
//
#include <hip/hip_runtime.h>
#include <hip/hip_bf16.h>

// Problem constants
constexpr int NQ   = 4096;   // spatial tokens (H*W)
constexpr int NKV  = 4112;   // spatial + 16 memory tokens
constexpr int NP   = 4160;   // padded rows (65 * 64), pad is zeroed
constexpr int CDIM = 128;
constexpr int NSL  = 4;      // split-K slices (1024 keys each; slice 3 + tail)
constexpr float QSC = 0.17677669529663687f * 1.4426950408889634f; // DH^-0.5 * log2(e)

typedef __attribute__((ext_vector_type(8)))  short bf16x8;
typedef __attribute__((ext_vector_type(4)))  short bf16x4;
typedef __attribute__((ext_vector_type(4)))  unsigned short u16x4;
typedef __attribute__((ext_vector_type(4)))  float f32x4;
typedef __attribute__((ext_vector_type(16))) float f32x16;

static __device__ __forceinline__ unsigned short bfbits(float f) {
  __hip_bfloat16 h = __float2bfloat16(f);
  return *reinterpret_cast<unsigned short*>(&h);
}
static __device__ __forceinline__ unsigned pk2(float a, float b) {
  return (unsigned)bfbits(a) | ((unsigned)bfbits(b) << 16);
}
static __device__ __forceinline__ float b2f(unsigned short u) {
  unsigned x = (unsigned)u << 16;
  return *reinterpret_cast<float*>(&x);
}

// ---------------- Kernel 1: QKV projection (+ w_out cast) ----------------
// grid (65, 4 batches, 2 o-halves), block 256 (4 waves, 3 o-tiles each).
//   Qt[bh][n][d] (bf16, pre-scaled by QSC), Kt[bh][n][d], Vt[bh][d][n]
__global__ __launch_bounds__(256) void k1_qkv(
    const float* __restrict__ x, const float* __restrict__ memry,
    const float* __restrict__ wqkv, const float* __restrict__ wout,
    __hip_bfloat16* __restrict__ Qt, __hip_bfloat16* __restrict__ Kt,
    __hip_bfloat16* __restrict__ Vt, __hip_bfloat16* __restrict__ Wb) {
  __shared__ __align__(16) __hip_bfloat16 xt[64][136];  // [n-local][c], +8 pad
  const int b  = blockIdx.y;
  const int zz = blockIdx.z;                   // o-half: 0 -> tiles 0-11, 1 -> 12-23
  const int nb = blockIdx.x * 64;
  const int t  = threadIdx.x;
  const int wv = t >> 6, ln = t & 63;

  if (blockIdx.x == 0 && b == 0 && zz == 0) {
    for (int i = t; i < CDIM * CDIM; i += 256) Wb[i] = __float2bfloat16(wout[i]);
  }

  { // stage x_ext tile (transposed, bf16)
    const int n = nb + ln;
    #pragma unroll
    for (int i = 0; i < 16; ++i) {
      const int c = wv * 32 + 2 * i;
      float v0 = 0.f, v1 = 0.f;
      if (n < NQ)        { v0 = x[((size_t)b * CDIM + c) * NQ + n];
                           v1 = x[((size_t)b * CDIM + c + 1) * NQ + n]; }
      else if (n < NKV)  { v0 = memry[c * 16 + (n - NQ)];
                           v1 = memry[(c + 1) * 16 + (n - NQ)]; }
      *reinterpret_cast<unsigned*>(&xt[ln][c]) =
          (unsigned)bfbits(v0) | ((unsigned)bfbits(v1) << 16);
    }
  }
  __syncthreads();

  const int li = ln & 15, g = ln >> 4;
  bf16x8 xa[4][4];
  #pragma unroll
  for (int nt = 0; nt < 4; ++nt)
    #pragma unroll
    for (int k = 0; k < 4; ++k)
      xa[nt][k] = *reinterpret_cast<const bf16x8*>(&xt[nt * 16 + li][k * 32 + 8 * g]);

  #pragma unroll
  for (int oi = 0; oi < 3; ++oi) {
    const int ot = zz * 12 + wv * 3 + oi;       // 24 o-tiles: 0-7 Q, 8-15 K, 16-23 V
    bf16x8 wf[4];
    #pragma unroll
    for (int k = 0; k < 4; ++k) {
      const float* wp = &wqkv[(size_t)(ot * 16 + li) * CDIM + k * 32 + 8 * g];
      const float4 f0 = *reinterpret_cast<const float4*>(wp);
      const float4 f1 = *reinterpret_cast<const float4*>(wp + 4);
      bf16x8 wc;
      wc[0] = (short)bfbits(f0.x); wc[1] = (short)bfbits(f0.y);
      wc[2] = (short)bfbits(f0.z); wc[3] = (short)bfbits(f0.w);
      wc[4] = (short)bfbits(f1.x); wc[5] = (short)bfbits(f1.y);
      wc[6] = (short)bfbits(f1.z); wc[7] = (short)bfbits(f1.w);
      wf[k] = wc;
    }
    #pragma unroll
    for (int nt = 0; nt < 4; ++nt) {
      f32x4 a; a[0] = a[1] = a[2] = a[3] = 0.f;
      if (ot < 16) {
        // D[row=n][col=o]  (A = x-tile, B = W^T)
        #pragma unroll
        for (int k = 0; k < 4; ++k)
          a = __builtin_amdgcn_mfma_f32_16x16x32_bf16(xa[nt][k], wf[k], a, 0, 0, 0);
        const int o = ot * 16 + li;
        const int h = (o >> 5) & 3, d = o & 31;
        if (ot < 8) {
          #pragma unroll
          for (int r = 0; r < 4; ++r) {
            const int n = nb + nt * 16 + 4 * g + r;
            Qt[((size_t)(b * 4 + h) * NP + n) * 32 + d] = __float2bfloat16(a[r] * QSC);
          }
        } else {
          #pragma unroll
          for (int r = 0; r < 4; ++r) {
            const int n = nb + nt * 16 + 4 * g + r;
            Kt[((size_t)(b * 4 + h) * NP + n) * 32 + d] = __float2bfloat16(a[r]);
          }
        }
      } else {
        // D[row=o][col=n]  (A = W, B = x-tile)
        #pragma unroll
        for (int k = 0; k < 4; ++k)
          a = __builtin_amdgcn_mfma_f32_16x16x32_bf16(wf[k], xa[nt][k], a, 0, 0, 0);
        #pragma unroll
        for (int r = 0; r < 4; ++r) {
          const int o = ot * 16 + 4 * g + r;
          const int h = (o >> 5) & 3, d = o & 31;
          const int n = nb + nt * 16 + li;
          Vt[((size_t)(b * 4 + h) * 32 + d) * NP + n] = __float2bfloat16(a[r]);
        }
      }
    }
  }
}

// ---- Kernel 2: attention partials; 64 q/wave, conflict-free V LDS ----
// Issue-bound now (VALUBusy 59 + MfmaUtil 34 = 93%). This round: persistent
// zero accumulator (kills 64 v_mov/tile), bf16 P partials (halves epilogue
// write; partials are unnormalized so bf16 error ~2e-5 after normalization),
// s_setprio(1) around MFMA clusters (T5).
// grid 1024 flat blocks (XCD-pinned), block 256 = 4 waves, 64 q per wave.

#if __has_builtin(__builtin_amdgcn_mfma_f32_32x32x8bf16_1k)
#define HAS_PV8 1
#else
#define HAS_PV8 0
#endif

#if HAS_PV8
__device__ __forceinline__ void half32(
    const bf16x8& kf0, const bf16x8& kf1,
    const bf16x4& vf0, const bf16x4& vf1, const bf16x4& vf2, const bf16x4& vf3,
    const bf16x8& q0, const bf16x8& q1, const f32x16& z,
    f32x16& acc, float& l0, float& l1, float& l2, float& l3) {
  __builtin_amdgcn_s_setprio(1);
  f32x16 s = __builtin_amdgcn_mfma_f32_32x32x16_bf16(kf0, q0, z, 0, 0, 0);
  s = __builtin_amdgcn_mfma_f32_32x32x16_bf16(kf1, q1, s, 0, 0, 0);
  __builtin_amdgcn_s_setprio(0);
  float p[16];
  #pragma unroll
  for (int r = 0; r < 16; ++r) p[r] = __builtin_amdgcn_exp2f(s[r]);
  l0 += (p[0] + p[1]) + (p[2] + p[3]);
  l1 += (p[4] + p[5]) + (p[6] + p[7]);
  l2 += (p[8] + p[9]) + (p[10] + p[11]);
  l3 += (p[12] + p[13]) + (p[14] + p[15]);
  union UU { unsigned u[2]; bf16x4 v; };
  UU a0, a1, a2, a3;  // quad r -> keys {0,8,16,24} + 4*hi + 0..3
  a0.u[0] = pk2(p[0], p[1]);   a0.u[1] = pk2(p[2], p[3]);
  a1.u[0] = pk2(p[4], p[5]);   a1.u[1] = pk2(p[6], p[7]);
  a2.u[0] = pk2(p[8], p[9]);   a2.u[1] = pk2(p[10], p[11]);
  a3.u[0] = pk2(p[12], p[13]); a3.u[1] = pk2(p[14], p[15]);
  __builtin_amdgcn_s_setprio(1);
  acc = __builtin_amdgcn_mfma_f32_32x32x8bf16_1k(a0.v, vf0, acc, 0, 0, 0);
  acc = __builtin_amdgcn_mfma_f32_32x32x8bf16_1k(a1.v, vf1, acc, 0, 0, 0);
  acc = __builtin_amdgcn_mfma_f32_32x32x8bf16_1k(a2.v, vf2, acc, 0, 0, 0);
  acc = __builtin_amdgcn_mfma_f32_32x32x8bf16_1k(a3.v, vf3, acc, 0, 0, 0);
  __builtin_amdgcn_s_setprio(0);
}
#else
__device__ __forceinline__ void half32_fb(
    const bf16x8& kf0, const bf16x8& kf1,
    const bf16x8& vh0, const bf16x8& vh1, int hi,
    const bf16x8& q0, const bf16x8& q1, const f32x16& z,
    f32x16& acc, float& l0, float& l1, float& l2, float& l3) {
  f32x16 s = __builtin_amdgcn_mfma_f32_32x32x16_bf16(kf0, q0, z, 0, 0, 0);
  s = __builtin_amdgcn_mfma_f32_32x32x16_bf16(kf1, q1, s, 0, 0, 0);
  float p[16];
  #pragma unroll
  for (int r = 0; r < 16; ++r) p[r] = __builtin_amdgcn_exp2f(s[r]);
  l0 += (p[0] + p[1]) + (p[2] + p[3]);
  l1 += (p[4] + p[5]) + (p[6] + p[7]);
  l2 += (p[8] + p[9]) + (p[10] + p[11]);
  l3 += (p[12] + p[13]) + (p[14] + p[15]);
  unsigned a0u0 = pk2(p[0], p[1]),   a0u1 = pk2(p[2], p[3]);
  unsigned a1u0 = pk2(p[4], p[5]),   a1u1 = pk2(p[6], p[7]);
  unsigned a2u0 = pk2(p[8], p[9]),   a2u1 = pk2(p[10], p[11]);
  unsigned a3u0 = pk2(p[12], p[13]), a3u1 = pk2(p[14], p[15]);
  union U8 { unsigned u[4]; bf16x8 v; };
  {
    const unsigned s0 = __shfl_xor(hi ? a0u0 : a1u0, 32, 64);
    const unsigned s1 = __shfl_xor(hi ? a0u1 : a1u1, 32, 64);
    U8 f;
    f.u[0] = hi ? s0 : a0u0; f.u[1] = hi ? s1 : a0u1;
    f.u[2] = hi ? a1u0 : s0; f.u[3] = hi ? a1u1 : s1;
    acc = __builtin_amdgcn_mfma_f32_32x32x16_bf16(f.v, vh0, acc, 0, 0, 0);
  }
  {
    const unsigned s0 = __shfl_xor(hi ? a2u0 : a3u0, 32, 64);
    const unsigned s1 = __shfl_xor(hi ? a2u1 : a3u1, 32, 64);
    U8 f;
    f.u[0] = hi ? s0 : a2u0; f.u[1] = hi ? s1 : a2u1;
    f.u[2] = hi ? a3u0 : s0; f.u[3] = hi ? a3u1 : s1;
    acc = __builtin_amdgcn_mfma_f32_32x32x16_bf16(f.v, vh1, acc, 0, 0, 0);
  }
}
#endif

__global__ __launch_bounds__(256, 3) void k2_attn(
    const __hip_bfloat16* __restrict__ Qt, const __hip_bfloat16* __restrict__ Kt,
    const __hip_bfloat16* __restrict__ Vt, __hip_bfloat16* __restrict__ Pb,
    float* __restrict__ Lb) {
  // two 8KB staging buffers: [K 4KB | V 4KB] each
  __shared__ __align__(16) unsigned char smem[16384];

  // XCD-pinned decomposition (assumes xcd = blockIdx % 8; perf-only heuristic)
  const int wg  = blockIdx.x;          // 0..1023
  const int xcd = wg & 7;
  const int i   = wg >> 3;             // 0..127
  const int bh  = 2 * xcd + (i & 1);   // 2 bh per XCD
  const int sl  = (i >> 1) & 3;        // split-K slice 0..3
  const int iq  = i >> 3;              // 0..15 -> 256-q block
  const int wv  = threadIdx.x >> 6, lane = threadIdx.x & 63;
  const int lq  = lane & 31, hi = lane >> 5;
  const int qbase = iq * 256 + wv * 64;   // this wave's 64 queries

  const bf16x8 qA0 = *reinterpret_cast<const bf16x8*>(
      Qt + ((size_t)bh * NP + qbase + lq) * 32 + 8 * hi);
  const bf16x8 qA1 = *reinterpret_cast<const bf16x8*>(
      Qt + ((size_t)bh * NP + qbase + lq) * 32 + 16 + 8 * hi);
  const bf16x8 qB0 = *reinterpret_cast<const bf16x8*>(
      Qt + ((size_t)bh * NP + qbase + 32 + lq) * 32 + 8 * hi);
  const bf16x8 qB1 = *reinterpret_cast<const bf16x8*>(
      Qt + ((size_t)bh * NP + qbase + 32 + lq) * 32 + 16 + 8 * hi);

  // staging sources (wave wv owns 1KB chunk of K-tile and V-tile)
  const int kb0 = sl * 1024;
  const __hip_bfloat16* Ksrc = Kt + ((size_t)bh * NP + kb0 + (wv >> 1) * 32 + lq) * 32
                                  + (wv & 1) * 16 + 8 * hi;
  const __hip_bfloat16* Vsrc = Vt + ((size_t)bh * 32 + lq) * NP + kb0 + wv * 16 + 8 * hi;
  const int kdst = wv * 1024 + lane * 16;  // byte off, K region
  // V write: keys wv*16+hi*8..+8 for d=lq -> two 8B granules at vdst, vdst+256
  const int vdst = (wv >> 1) * 2048 + ((wv & 1) * 2 + hi) * 512 + lq * 8;
  const int rdv  = hi * 256 + lq * 8;      // V read base (contiguous per op)

  f32x16 accA, accB, z;
  #pragma unroll
  for (int q = 0; q < 16; ++q) { accA[q] = 0.f; accB[q] = 0.f; z[q] = 0.f; }
  float la0 = 0.f, la1 = 0.f, la2 = 0.f, la3 = 0.f;
  float lb0 = 0.f, lb1 = 0.f, lb2 = 0.f, lb3 = 0.f;

  bf16x8 kreg = *reinterpret_cast<const bf16x8*>(Ksrc);
  bf16x8 vreg = *reinterpret_cast<const bf16x8*>(Vsrc);

#define WRITE_KV(basep)                                                        \
  {                                                                            \
    *reinterpret_cast<bf16x8*>((basep) + kdst) = kreg;                         \
    bf16x4 vlo, vhi;                                                           \
    vlo[0] = vreg[0]; vlo[1] = vreg[1]; vlo[2] = vreg[2]; vlo[3] = vreg[3];    \
    vhi[0] = vreg[4]; vhi[1] = vreg[5]; vhi[2] = vreg[6]; vhi[3] = vreg[7];    \
    *reinterpret_cast<bf16x4*>((basep) + 4096 + vdst)       = vlo;             \
    *reinterpret_cast<bf16x4*>((basep) + 4096 + vdst + 256) = vhi;             \
  }

  // prologue: tile 0 -> buf0; tile 1 loads in flight
  WRITE_KV(smem)
  kreg = *reinterpret_cast<const bf16x8*>(Ksrc + 2048);
  vreg = *reinterpret_cast<const bf16x8*>(Vsrc + 64);

  for (int t = 0; t < 16; ++t) {
    __syncthreads();   // buf[t&1] ready; all reads of buf[(t+1)&1] drained
    const int p = t & 1;
    if (t < 15) {
      unsigned char* nbuf = smem + (p ^ 1) * 8192;
      WRITE_KV(nbuf)
      if (t < 14) {
        kreg = *reinterpret_cast<const bf16x8*>(Ksrc + (size_t)(t + 2) * 2048);
        vreg = *reinterpret_cast<const bf16x8*>(Vsrc + (t + 2) * 64);
      }
    }
    const unsigned char* kbuf = smem + p * 8192;
    const unsigned char* vbase = kbuf + 4096;

    #pragma unroll
    for (int st = 0; st < 2; ++st) {           // two 32-key subtiles
      const bf16x8 kf0 = *reinterpret_cast<const bf16x8*>(kbuf + st * 2048 + lane * 16);
      const bf16x8 kf1 = *reinterpret_cast<const bf16x8*>(kbuf + st * 2048 + 1024 + lane * 16);
#if HAS_PV8
      const unsigned char* vb = vbase + st * 2048;
      const bf16x4 vf0 = *reinterpret_cast<const bf16x4*>(vb + rdv);
      const bf16x4 vf1 = *reinterpret_cast<const bf16x4*>(vb + 512 + rdv);
      const bf16x4 vf2 = *reinterpret_cast<const bf16x4*>(vb + 1024 + rdv);
      const bf16x4 vf3 = *reinterpret_cast<const bf16x4*>(vb + 1536 + rdv);
      half32(kf0, kf1, vf0, vf1, vf2, vf3, qA0, qA1, z, accA, la0, la1, la2, la3);
      half32(kf0, kf1, vf0, vf1, vf2, vf3, qB0, qB1, z, accB, lb0, lb1, lb2, lb3);
#else
      const unsigned char* vb = vbase + st * 2048;
      union { bf16x4 h[2]; bf16x8 w; } vh0, vh1;
      vh0.h[0] = *reinterpret_cast<const bf16x4*>(vb + hi * 512 + lq * 8);
      vh0.h[1] = *reinterpret_cast<const bf16x4*>(vb + hi * 512 + 256 + lq * 8);
      vh1.h[0] = *reinterpret_cast<const bf16x4*>(vb + (2 + hi) * 512 + lq * 8);
      vh1.h[1] = *reinterpret_cast<const bf16x4*>(vb + (2 + hi) * 512 + 256 + lq * 8);
      half32_fb(kf0, kf1, vh0.w, vh1.w, hi, qA0, qA1, z, accA, la0, la1, la2, la3);
      half32_fb(kf0, kf1, vh0.w, vh1.w, hi, qB0, qB1, z, accB, lb0, lb1, lb2, lb3);
#endif
    }
  }
#undef WRITE_KV

  if (sl == NSL - 1) {
    // tail: 16 real keys (4096..4111), direct from global (L2-hot, tiny)
    const __hip_bfloat16* Kp   = Kt + (size_t)bh * NP * 32 + (size_t)lq * 32 + 8 * hi;
    const __hip_bfloat16* Vrow = Vt + ((size_t)bh * 32 + lq) * NP;
    const int kb = 4096;
    const bf16x8 kf0 = *reinterpret_cast<const bf16x8*>(Kp + (size_t)kb * 32);
    const bf16x8 kf1 = *reinterpret_cast<const bf16x8*>(Kp + (size_t)kb * 32 + 16);
#if HAS_PV8
    const bf16x4 vt0 = *reinterpret_cast<const bf16x4*>(Vrow + kb + 4 * hi);
    const bf16x4 vt1 = *reinterpret_cast<const bf16x4*>(Vrow + kb + 8 + 4 * hi);
#else
    const bf16x8 vt8 = *reinterpret_cast<const bf16x8*>(Vrow + kb + 8 * hi);
#endif
    #pragma unroll
    for (int hf = 0; hf < 2; ++hf) {
      const bf16x8 q0 = hf ? qB0 : qA0;
      const bf16x8 q1 = hf ? qB1 : qA1;
      f32x16 s = __builtin_amdgcn_mfma_f32_32x32x16_bf16(kf0, q0, z, 0, 0, 0);
      s = __builtin_amdgcn_mfma_f32_32x32x16_bf16(kf1, q1, s, 0, 0, 0);
      float p_[8];
      #pragma unroll
      for (int r = 0; r < 8; ++r) p_[r] = __builtin_amdgcn_exp2f(s[r]);
      const float s01 = (p_[0] + p_[1]) + (p_[2] + p_[3]);
      const float s23 = (p_[4] + p_[5]) + (p_[6] + p_[7]);
      if (hf) { lb0 += s01; lb1 += s23; } else { la0 += s01; la1 += s23; }
#if HAS_PV8
      union UU { unsigned u[2]; bf16x4 v; };
      UU a0, a1;
      a0.u[0] = pk2(p_[0], p_[1]); a0.u[1] = pk2(p_[2], p_[3]);
      a1.u[0] = pk2(p_[4], p_[5]); a1.u[1] = pk2(p_[6], p_[7]);
      if (hf) {
        accB = __builtin_amdgcn_mfma_f32_32x32x8bf16_1k(a0.v, vt0, accB, 0, 0, 0);
        accB = __builtin_amdgcn_mfma_f32_32x32x8bf16_1k(a1.v, vt1, accB, 0, 0, 0);
      } else {
        accA = __builtin_amdgcn_mfma_f32_32x32x8bf16_1k(a0.v, vt0, accA, 0, 0, 0);
        accA = __builtin_amdgcn_mfma_f32_32x32x8bf16_1k(a1.v, vt1, accA, 0, 0, 0);
      }
#else
      unsigned a0u0 = pk2(p_[0], p_[1]), a0u1 = pk2(p_[2], p_[3]);
      unsigned a1u0 = pk2(p_[4], p_[5]), a1u1 = pk2(p_[6], p_[7]);
      union U8 { unsigned u[4]; bf16x8 v; };
      const unsigned s0 = __shfl_xor(hi ? a0u0 : a1u0, 32, 64);
      const unsigned s1 = __shfl_xor(hi ? a0u1 : a1u1, 32, 64);
      U8 f;
      f.u[0] = hi ? s0 : a0u0; f.u[1] = hi ? s1 : a0u1;
      f.u[2] = hi ? a1u0 : s0; f.u[3] = hi ? a1u1 : s1;
      if (hf) accB = __builtin_amdgcn_mfma_f32_32x32x16_bf16(f.v, vt8, accB, 0, 0, 0);
      else    accA = __builtin_amdgcn_mfma_f32_32x32x16_bf16(f.v, vt8, accA, 0, 0, 0);
#endif
    }
  }

  // write partials: P[sl][bh][q][d] (bf16, d = lq), L[sl][bh][q], both q-halves
  __hip_bfloat16* PpA = Pb + (((size_t)sl * 16 + bh) * NQ + qbase) * 32;
  #pragma unroll
  for (int r = 0; r < 16; ++r) {
    const int q = (r & 3) + 8 * (r >> 2) + 4 * hi;
    PpA[(size_t)q * 32 + lq] = __float2bfloat16(accA[r]);
    PpA[(size_t)(q + 32) * 32 + lq] = __float2bfloat16(accB[r]);
  }
  float lsA = (la0 + la1) + (la2 + la3);
  float lsB = (lb0 + lb1) + (lb2 + lb3);
  lsA += __shfl_xor(lsA, 32, 64);
  lsB += __shfl_xor(lsB, 32, 64);
  if (hi == 0) {
    Lb[((size_t)sl * 16 + bh) * NQ + qbase + lq] = lsA;
    Lb[((size_t)sl * 16 + bh) * NQ + qbase + 32 + lq] = lsB;
  }
}

// ---------------- Kernel 2b: combine split-K partials ----------------
// att[bh][q][d] = (sum_s P[s][bh][q][d]) / (sum_s L[s][bh][q])   (bf16)
// grid 2048 x 256: XCD-pinned; P now bf16 -> 2.1 MB/XCD, L2-resident.
__global__ __launch_bounds__(256) void k2b_combine(
    const __hip_bfloat16* __restrict__ Pb, const float* __restrict__ Lb,
    __hip_bfloat16* __restrict__ att) {
  constexpr size_t PS = (size_t)16 * NQ * 32;       // per-slice P elements
  constexpr size_t LS = (size_t)16 * NQ;            // per-slice L elements
  const int wg  = blockIdx.x;          // 0..2047
  const int xcd = wg & 7;
  const int i   = wg >> 3;             // 0..255
  const int bh  = 2 * xcd + (i & 1);   // matches k2's bh->XCD pinning
  const int j   = i >> 1;              // 0..127
  const int u   = j * 256 + threadIdx.x;   // 0..32767 per bh
  const int q   = u >> 3;
  const int d0  = (u & 7) * 4;
  const size_t qi = (size_t)bh * NQ + q;

  float l = 0.f;
  #pragma unroll
  for (int s = 0; s < NSL; ++s) l += Lb[s * LS + qi];
  const float inv = 1.f / l;

  float4 o = make_float4(0.f, 0.f, 0.f, 0.f);
  #pragma unroll
  for (int s = 0; s < NSL; ++s) {
    const u16x4 f = *reinterpret_cast<const u16x4*>(Pb + s * PS + qi * 32 + d0);
    o.x += b2f(f[0]); o.y += b2f(f[1]); o.z += b2f(f[2]); o.w += b2f(f[3]);
  }
  *reinterpret_cast<uint2*>(att + qi * 32 + d0) =
      make_uint2(pk2(o.x * inv, o.y * inv), pk2(o.z * inv, o.w * inv));
}

// ---------------- Kernel 3: output projection ----------------
// grid (128 n-tiles, 4 batches), block 256 (4 waves, 2 o-tiles each).
// att layout is (bh, q, d): head k, d-range 8g..8g+7 for row n.
__global__ __launch_bounds__(256) void k3_proj(
    const __hip_bfloat16* __restrict__ att, const __hip_bfloat16* __restrict__ Wb,
    const float* __restrict__ bout, float* __restrict__ out) {
  const int b = blockIdx.y, nb = blockIdx.x * 32;
  const int wv = threadIdx.x >> 6, lane = threadIdx.x & 63;
  const int li = lane & 15, g = lane >> 4;

  bf16x8 wf[2][4];
  float bo[2][4];
  #pragma unroll
  for (int tt = 0; tt < 2; ++tt) {
    const int ot = 2 * wv + tt;
    #pragma unroll
    for (int k = 0; k < 4; ++k)
      wf[tt][k] = *reinterpret_cast<const bf16x8*>(
          &Wb[(size_t)(ot * 16 + li) * CDIM + k * 32 + 8 * g]);
    #pragma unroll
    for (int r = 0; r < 4; ++r) bo[tt][r] = bout[ot * 16 + 4 * g + r];
  }
  #pragma unroll
  for (int nt = 0; nt < 2; ++nt) {
    bf16x8 bfr[4];
    #pragma unroll
    for (int k = 0; k < 4; ++k)
      bfr[k] = *reinterpret_cast<const bf16x8*>(
          &att[(((size_t)(b * 4 + k)) * NQ + nb + nt * 16 + li) * 32 + 8 * g]);
    #pragma unroll
    for (int tt = 0; tt < 2; ++tt) {
      f32x4 a; a[0] = a[1] = a[2] = a[3] = 0.f;
      #pragma unroll
      for (int k = 0; k < 4; ++k)
        a = __builtin_amdgcn_mfma_f32_16x16x32_bf16(wf[tt][k], bfr[k], a, 0, 0, 0);
      const int ot = 2 * wv + tt;
      #pragma unroll
      for (int r = 0; r < 4; ++r)
        out[((size_t)b * CDIM + ot * 16 + 4 * g + r) * NQ + nb + nt * 16 + li] =
            a[r] + bo[tt][r];
    }
  }
}

extern "C" void kernel_launch(void* const* d_in, const int* in_sizes, int n_in,
                              void* d_out, int out_size, void* d_ws, size_t ws_size,
                              hipStream_t stream) {
  const float* x    = (const float*)d_in[0];
  const float* memp = (const float*)d_in[1];
  const float* wqkv = (const float*)d_in[2];
  const float* wout = (const float*)d_in[3];
  const float* bout = (const float*)d_in[4];
  float* out = (float*)d_out;

  char* ws = (char*)d_ws;
  const size_t SZ  = (size_t)16 * NP * 32 * 2;              // Qt/Kt/Vt each
  const size_t PSZ = (size_t)NSL * 16 * NQ * 32 * 2;        // 16.8 MB (bf16)
  const size_t LSZ = (size_t)NSL * 16 * NQ * 4;             // 1 MB
  const size_t ASZ = (size_t)16 * NQ * 32 * 2;              // att (bh,q,d) bf16
  __hip_bfloat16* Qt  = (__hip_bfloat16*)(ws);
  __hip_bfloat16* Kt  = (__hip_bfloat16*)(ws + SZ);
  __hip_bfloat16* Vt  = (__hip_bfloat16*)(ws + 2 * SZ);
  __hip_bfloat16* Pbf = (__hip_bfloat16*)(ws + 3 * SZ);
  float*          Lbf = (float*)(ws + 3 * SZ + PSZ);
  __hip_bfloat16* att = (__hip_bfloat16*)(ws + 3 * SZ + PSZ + LSZ);
  __hip_bfloat16* Wb  = (__hip_bfloat16*)(ws + 3 * SZ + PSZ + LSZ + ASZ);

  hipLaunchKernelGGL(k1_qkv, dim3(65, 4, 2), dim3(256), 0, stream,
                     x, memp, wqkv, wout, Qt, Kt, Vt, Wb);
  hipLaunchKernelGGL(k2_attn, dim3(1024), dim3(256), 0, stream,
                     Qt, Kt, Vt, Pbf, Lbf);
  hipLaunchKernelGGL(k2b_combine, dim3(2048), dim3(256), 0, stream, Pbf, Lbf, att);
  hipLaunchKernelGGL(k3_proj, dim3(128, 4), dim3(256), 0, stream, att, Wb, bout, out);
}

// Round 13
// 89.230 us; speedup vs baseline: 1.0690x; 1.0690x over previous
//
#include <hip/hip_runtime.h>
#include <hip/hip_bf16.h>

// Problem constants
constexpr int NQ   = 4096;   // spatial tokens (H*W)
constexpr int NKV  = 4112;   // spatial + 16 memory tokens
constexpr int NP   = 4160;   // padded rows (65 * 64), pad is zeroed
constexpr int CDIM = 128;
constexpr int NSL  = 4;      // split-K slices (1024 keys each; slice 3 + tail)
constexpr int VTILE = 2048;  // V tile: 64 keys x 32 d (elements)
constexpr float QSC = 0.17677669529663687f * 1.4426950408889634f; // DH^-0.5 * log2(e)

typedef __attribute__((ext_vector_type(8)))  short bf16x8;
typedef __attribute__((ext_vector_type(4)))  short bf16x4;
typedef __attribute__((ext_vector_type(4)))  unsigned short u16x4;
typedef __attribute__((ext_vector_type(4)))  float f32x4;
typedef __attribute__((ext_vector_type(16))) float f32x16;

static __device__ __forceinline__ unsigned short bfbits(float f) {
  __hip_bfloat16 h = __float2bfloat16(f);
  return *reinterpret_cast<unsigned short*>(&h);
}
static __device__ __forceinline__ unsigned pk2(float a, float b) {
  return (unsigned)bfbits(a) | ((unsigned)bfbits(b) << 16);
}
static __device__ __forceinline__ float b2f(unsigned short u) {
  unsigned x = (unsigned)u << 16;
  return *reinterpret_cast<float*>(&x);
}

// async global->LDS, 16B per lane; LDS dest = wave-uniform base + lane*16
#define GLOAD_LDS16(gsrc, ldst)                                               \
  __builtin_amdgcn_global_load_lds(                                           \
      (const __attribute__((address_space(1))) unsigned int*)(gsrc),          \
      (__attribute__((address_space(3))) unsigned int*)(ldst), 16, 0, 0)

// ---------------- Kernel 1: QKV projection (+ w_out cast) ----------------
// grid (65, 4 batches, 2 o-halves), block 256 (4 waves, 3 o-tiles each).
//   Qt[bh][n][d] (bf16, pre-scaled by QSC), Kt[bh][n][d],
//   Vt: per-64-key-tile fragment image (matches k2's LDS layout exactly):
//     elem(d, n) = bh*65*VTILE + (n>>6)*VTILE + ((n>>5)&1)*1024
//                + ((n>>3)&3)*256 + ((n>>2)&1)*128 + d*4 + (n&3)
__global__ __launch_bounds__(256) void k1_qkv(
    const float* __restrict__ x, const float* __restrict__ memry,
    const float* __restrict__ wqkv, const float* __restrict__ wout,
    __hip_bfloat16* __restrict__ Qt, __hip_bfloat16* __restrict__ Kt,
    __hip_bfloat16* __restrict__ Vt, __hip_bfloat16* __restrict__ Wb) {
  __shared__ __align__(16) __hip_bfloat16 xt[64][136];  // [n-local][c], +8 pad
  const int b  = blockIdx.y;
  const int zz = blockIdx.z;                   // o-half: 0 -> tiles 0-11, 1 -> 12-23
  const int nb = blockIdx.x * 64;
  const int t  = threadIdx.x;
  const int wv = t >> 6, ln = t & 63;

  if (blockIdx.x == 0 && b == 0 && zz == 0) {
    for (int i = t; i < CDIM * CDIM; i += 256) Wb[i] = __float2bfloat16(wout[i]);
  }

  { // stage x_ext tile (transposed, bf16)
    const int n = nb + ln;
    #pragma unroll
    for (int i = 0; i < 16; ++i) {
      const int c = wv * 32 + 2 * i;
      float v0 = 0.f, v1 = 0.f;
      if (n < NQ)        { v0 = x[((size_t)b * CDIM + c) * NQ + n];
                           v1 = x[((size_t)b * CDIM + c + 1) * NQ + n]; }
      else if (n < NKV)  { v0 = memry[c * 16 + (n - NQ)];
                           v1 = memry[(c + 1) * 16 + (n - NQ)]; }
      *reinterpret_cast<unsigned*>(&xt[ln][c]) =
          (unsigned)bfbits(v0) | ((unsigned)bfbits(v1) << 16);
    }
  }
  __syncthreads();

  const int li = ln & 15, g = ln >> 4;
  bf16x8 xa[4][4];
  #pragma unroll
  for (int nt = 0; nt < 4; ++nt)
    #pragma unroll
    for (int k = 0; k < 4; ++k)
      xa[nt][k] = *reinterpret_cast<const bf16x8*>(&xt[nt * 16 + li][k * 32 + 8 * g]);

  #pragma unroll
  for (int oi = 0; oi < 3; ++oi) {
    const int ot = zz * 12 + wv * 3 + oi;       // 24 o-tiles: 0-7 Q, 8-15 K, 16-23 V
    bf16x8 wf[4];
    #pragma unroll
    for (int k = 0; k < 4; ++k) {
      const float* wp = &wqkv[(size_t)(ot * 16 + li) * CDIM + k * 32 + 8 * g];
      const float4 f0 = *reinterpret_cast<const float4*>(wp);
      const float4 f1 = *reinterpret_cast<const float4*>(wp + 4);
      bf16x8 wc;
      wc[0] = (short)bfbits(f0.x); wc[1] = (short)bfbits(f0.y);
      wc[2] = (short)bfbits(f0.z); wc[3] = (short)bfbits(f0.w);
      wc[4] = (short)bfbits(f1.x); wc[5] = (short)bfbits(f1.y);
      wc[6] = (short)bfbits(f1.z); wc[7] = (short)bfbits(f1.w);
      wf[k] = wc;
    }
    #pragma unroll
    for (int nt = 0; nt < 4; ++nt) {
      f32x4 a; a[0] = a[1] = a[2] = a[3] = 0.f;
      if (ot < 16) {
        // D[row=n][col=o]  (A = x-tile, B = W^T)
        #pragma unroll
        for (int k = 0; k < 4; ++k)
          a = __builtin_amdgcn_mfma_f32_16x16x32_bf16(xa[nt][k], wf[k], a, 0, 0, 0);
        const int o = ot * 16 + li;
        const int h = (o >> 5) & 3, d = o & 31;
        if (ot < 8) {
          #pragma unroll
          for (int r = 0; r < 4; ++r) {
            const int n = nb + nt * 16 + 4 * g + r;
            Qt[((size_t)(b * 4 + h) * NP + n) * 32 + d] = __float2bfloat16(a[r] * QSC);
          }
        } else {
          #pragma unroll
          for (int r = 0; r < 4; ++r) {
            const int n = nb + nt * 16 + 4 * g + r;
            Kt[((size_t)(b * 4 + h) * NP + n) * 32 + d] = __float2bfloat16(a[r]);
          }
        }
      } else {
        // D[row=o][col=n]  (A = W, B = x-tile); V in tile-fragment order
        #pragma unroll
        for (int k = 0; k < 4; ++k)
          a = __builtin_amdgcn_mfma_f32_16x16x32_bf16(wf[k], xa[nt][k], a, 0, 0, 0);
        const int n = nb + nt * 16 + li;
        const size_t vb = (size_t)(b * 4) * 65 * VTILE       // h added below
                        + (size_t)(n >> 6) * VTILE + ((n >> 5) & 1) * 1024
                        + ((n >> 3) & 3) * 256 + ((n >> 2) & 1) * 128 + (n & 3);
        #pragma unroll
        for (int r = 0; r < 4; ++r) {
          const int o = ot * 16 + 4 * g + r;
          const int h = (o >> 5) & 3, d = o & 31;
          Vt[vb + (size_t)h * 65 * VTILE + d * 4] = __float2bfloat16(a[r]);
        }
      }
    }
  }
}

// ---- Kernel 2: attention partials; 64 q/wave, global_load_lds staging ----
// Issue-bound (VALUBusy+MfmaUtil ~90%). This round: K/V staged via
// global_load_lds (V pre-swizzled in global by k1 so the LDS image is
// linear lane*16) -> no reg round-trip, no ds_writes, no staging branches.
// setprio removed (lockstep-barrier kernel: m190 says it hurts).
// grid 1024 flat blocks (XCD-pinned), block 256 = 4 waves, 64 q per wave.

#if __has_builtin(__builtin_amdgcn_mfma_f32_32x32x8bf16_1k)
#define HAS_PV8 1
#else
#define HAS_PV8 0
#endif

#if HAS_PV8
__device__ __forceinline__ void half32(
    const bf16x8& kf0, const bf16x8& kf1,
    const bf16x4& vf0, const bf16x4& vf1, const bf16x4& vf2, const bf16x4& vf3,
    const bf16x8& q0, const bf16x8& q1, const f32x16& z,
    f32x16& acc, float& l0, float& l1, float& l2, float& l3) {
  f32x16 s = __builtin_amdgcn_mfma_f32_32x32x16_bf16(kf0, q0, z, 0, 0, 0);
  s = __builtin_amdgcn_mfma_f32_32x32x16_bf16(kf1, q1, s, 0, 0, 0);
  float p[16];
  #pragma unroll
  for (int r = 0; r < 16; ++r) p[r] = __builtin_amdgcn_exp2f(s[r]);
  l0 += (p[0] + p[1]) + (p[2] + p[3]);
  l1 += (p[4] + p[5]) + (p[6] + p[7]);
  l2 += (p[8] + p[9]) + (p[10] + p[11]);
  l3 += (p[12] + p[13]) + (p[14] + p[15]);
  union UU { unsigned u[2]; bf16x4 v; };
  UU a0, a1, a2, a3;  // quad r -> keys {0,8,16,24} + 4*hi + 0..3
  a0.u[0] = pk2(p[0], p[1]);   a0.u[1] = pk2(p[2], p[3]);
  a1.u[0] = pk2(p[4], p[5]);   a1.u[1] = pk2(p[6], p[7]);
  a2.u[0] = pk2(p[8], p[9]);   a2.u[1] = pk2(p[10], p[11]);
  a3.u[0] = pk2(p[12], p[13]); a3.u[1] = pk2(p[14], p[15]);
  acc = __builtin_amdgcn_mfma_f32_32x32x8bf16_1k(a0.v, vf0, acc, 0, 0, 0);
  acc = __builtin_amdgcn_mfma_f32_32x32x8bf16_1k(a1.v, vf1, acc, 0, 0, 0);
  acc = __builtin_amdgcn_mfma_f32_32x32x8bf16_1k(a2.v, vf2, acc, 0, 0, 0);
  acc = __builtin_amdgcn_mfma_f32_32x32x8bf16_1k(a3.v, vf3, acc, 0, 0, 0);
}
#else
__device__ __forceinline__ void half32_fb(
    const bf16x8& kf0, const bf16x8& kf1,
    const bf16x8& vh0, const bf16x8& vh1, int hi,
    const bf16x8& q0, const bf16x8& q1, const f32x16& z,
    f32x16& acc, float& l0, float& l1, float& l2, float& l3) {
  f32x16 s = __builtin_amdgcn_mfma_f32_32x32x16_bf16(kf0, q0, z, 0, 0, 0);
  s = __builtin_amdgcn_mfma_f32_32x32x16_bf16(kf1, q1, s, 0, 0, 0);
  float p[16];
  #pragma unroll
  for (int r = 0; r < 16; ++r) p[r] = __builtin_amdgcn_exp2f(s[r]);
  l0 += (p[0] + p[1]) + (p[2] + p[3]);
  l1 += (p[4] + p[5]) + (p[6] + p[7]);
  l2 += (p[8] + p[9]) + (p[10] + p[11]);
  l3 += (p[12] + p[13]) + (p[14] + p[15]);
  unsigned a0u0 = pk2(p[0], p[1]),   a0u1 = pk2(p[2], p[3]);
  unsigned a1u0 = pk2(p[4], p[5]),   a1u1 = pk2(p[6], p[7]);
  unsigned a2u0 = pk2(p[8], p[9]),   a2u1 = pk2(p[10], p[11]);
  unsigned a3u0 = pk2(p[12], p[13]), a3u1 = pk2(p[14], p[15]);
  union U8 { unsigned u[4]; bf16x8 v; };
  {
    const unsigned s0 = __shfl_xor(hi ? a0u0 : a1u0, 32, 64);
    const unsigned s1 = __shfl_xor(hi ? a0u1 : a1u1, 32, 64);
    U8 f;
    f.u[0] = hi ? s0 : a0u0; f.u[1] = hi ? s1 : a0u1;
    f.u[2] = hi ? a1u0 : s0; f.u[3] = hi ? a1u1 : s1;
    acc = __builtin_amdgcn_mfma_f32_32x32x16_bf16(f.v, vh0, acc, 0, 0, 0);
  }
  {
    const unsigned s0 = __shfl_xor(hi ? a2u0 : a3u0, 32, 64);
    const unsigned s1 = __shfl_xor(hi ? a2u1 : a3u1, 32, 64);
    U8 f;
    f.u[0] = hi ? s0 : a2u0; f.u[1] = hi ? s1 : a2u1;
    f.u[2] = hi ? a3u0 : s0; f.u[3] = hi ? a3u1 : s1;
    acc = __builtin_amdgcn_mfma_f32_32x32x16_bf16(f.v, vh1, acc, 0, 0, 0);
  }
}
#endif

__global__ __launch_bounds__(256, 3) void k2_attn(
    const __hip_bfloat16* __restrict__ Qt, const __hip_bfloat16* __restrict__ Kt,
    const __hip_bfloat16* __restrict__ Vt, __hip_bfloat16* __restrict__ Pb,
    float* __restrict__ Lb) {
  // two 8KB staging buffers: [K 4KB | V 4KB] each
  __shared__ __align__(16) unsigned char smem[16384];

  // XCD-pinned decomposition (assumes xcd = blockIdx % 8; perf-only heuristic)
  const int wg  = blockIdx.x;          // 0..1023
  const int xcd = wg & 7;
  const int i   = wg >> 3;             // 0..127
  const int bh  = 2 * xcd + (i & 1);   // 2 bh per XCD
  const int sl  = (i >> 1) & 3;        // split-K slice 0..3
  const int iq  = i >> 3;              // 0..15 -> 256-q block
  const int wv  = threadIdx.x >> 6, lane = threadIdx.x & 63;
  const int lq  = lane & 31, hi = lane >> 5;
  const int qbase = iq * 256 + wv * 64;   // this wave's 64 queries

  const bf16x8 qA0 = *reinterpret_cast<const bf16x8*>(
      Qt + ((size_t)bh * NP + qbase + lq) * 32 + 8 * hi);
  const bf16x8 qA1 = *reinterpret_cast<const bf16x8*>(
      Qt + ((size_t)bh * NP + qbase + lq) * 32 + 16 + 8 * hi);
  const bf16x8 qB0 = *reinterpret_cast<const bf16x8*>(
      Qt + ((size_t)bh * NP + qbase + 32 + lq) * 32 + 8 * hi);
  const bf16x8 qB1 = *reinterpret_cast<const bf16x8*>(
      Qt + ((size_t)bh * NP + qbase + 32 + lq) * 32 + 16 + 8 * hi);

  // staging sources: per-lane global addresses; tile stride = 2048 elements
  const int kb0 = sl * 1024;
  const __hip_bfloat16* Ksrc = Kt + ((size_t)bh * NP + kb0 + (wv >> 1) * 32 + lq) * 32
                                  + (wv & 1) * 16 + 8 * hi;
  const __hip_bfloat16* Vsrc = Vt + (size_t)bh * 65 * VTILE
                                  + (size_t)(kb0 >> 6) * VTILE + threadIdx.x * 8;
  // LDS dests: wave-uniform bases (HW adds lane*16)
  const int kofs = wv * 1024;          // within K region
  const int rdv  = hi * 256 + lq * 8;  // V read base (contiguous per op)

  f32x16 accA, accB, z;
  #pragma unroll
  for (int q = 0; q < 16; ++q) { accA[q] = 0.f; accB[q] = 0.f; z[q] = 0.f; }
  float la0 = 0.f, la1 = 0.f, la2 = 0.f, la3 = 0.f;
  float lb0 = 0.f, lb1 = 0.f, lb2 = 0.f, lb3 = 0.f;

  // prologue: tile 0 -> buf0 (DMA)
  GLOAD_LDS16(Ksrc, smem + kofs);
  GLOAD_LDS16(Vsrc, smem + 4096 + kofs);

  for (int t = 0; t < 16; ++t) {
    __syncthreads();   // drains outstanding global_load_lds into buf[t&1]
    const int p = t & 1;
    { // stage tile t+1 into the idle buffer (t=15 stages the valid pad tile)
      unsigned char* nbuf = smem + (p ^ 1) * 8192;
      GLOAD_LDS16(Ksrc + (size_t)(t + 1) * 2048, nbuf + kofs);
      GLOAD_LDS16(Vsrc + (size_t)(t + 1) * 2048, nbuf + 4096 + kofs);
    }
    const unsigned char* kbuf = smem + p * 8192;
    const unsigned char* vbase = kbuf + 4096;

    #pragma unroll
    for (int st = 0; st < 2; ++st) {           // two 32-key subtiles
      const bf16x8 kf0 = *reinterpret_cast<const bf16x8*>(kbuf + st * 2048 + lane * 16);
      const bf16x8 kf1 = *reinterpret_cast<const bf16x8*>(kbuf + st * 2048 + 1024 + lane * 16);
#if HAS_PV8
      const unsigned char* vb = vbase + st * 2048;
      const bf16x4 vf0 = *reinterpret_cast<const bf16x4*>(vb + rdv);
      const bf16x4 vf1 = *reinterpret_cast<const bf16x4*>(vb + 512 + rdv);
      const bf16x4 vf2 = *reinterpret_cast<const bf16x4*>(vb + 1024 + rdv);
      const bf16x4 vf3 = *reinterpret_cast<const bf16x4*>(vb + 1536 + rdv);
      half32(kf0, kf1, vf0, vf1, vf2, vf3, qA0, qA1, z, accA, la0, la1, la2, la3);
      half32(kf0, kf1, vf0, vf1, vf2, vf3, qB0, qB1, z, accB, lb0, lb1, lb2, lb3);
#else
      const unsigned char* vb = vbase + st * 2048;
      union { bf16x4 h[2]; bf16x8 w; } vh0, vh1;
      vh0.h[0] = *reinterpret_cast<const bf16x4*>(vb + hi * 512 + lq * 8);
      vh0.h[1] = *reinterpret_cast<const bf16x4*>(vb + hi * 512 + 256 + lq * 8);
      vh1.h[0] = *reinterpret_cast<const bf16x4*>(vb + (2 + hi) * 512 + lq * 8);
      vh1.h[1] = *reinterpret_cast<const bf16x4*>(vb + (2 + hi) * 512 + 256 + lq * 8);
      half32_fb(kf0, kf1, vh0.w, vh1.w, hi, qA0, qA1, z, accA, la0, la1, la2, la3);
      half32_fb(kf0, kf1, vh0.w, vh1.w, hi, qB0, qB1, z, accB, lb0, lb1, lb2, lb3);
#endif
    }
  }

  if (sl == NSL - 1) {
    // tail: 16 real keys (4096..4111), direct from global (L2-hot, tiny)
    const __hip_bfloat16* Kp = Kt + (size_t)bh * NP * 32 + (size_t)lq * 32 + 8 * hi;
    const __hip_bfloat16* Vtt = Vt + (size_t)bh * 65 * VTILE + (size_t)64 * VTILE;
    const int kb = 4096;
    const bf16x8 kf0 = *reinterpret_cast<const bf16x8*>(Kp + (size_t)kb * 32);
    const bf16x8 kf1 = *reinterpret_cast<const bf16x8*>(Kp + (size_t)kb * 32 + 16);
#if HAS_PV8
    // keys 4*hi+0..3 at hi*128+lq*4 elems; keys 8+4*hi at +256 elems
    const bf16x4 vt0 = *reinterpret_cast<const bf16x4*>(Vtt + hi * 128 + lq * 4);
    const bf16x4 vt1 = *reinterpret_cast<const bf16x4*>(Vtt + 256 + hi * 128 + lq * 4);
#else
    union { bf16x4 h[2]; bf16x8 w; } vt8u;
    vt8u.h[0] = *reinterpret_cast<const bf16x4*>(Vtt + hi * 256 + lq * 4 + 0);
    vt8u.h[1] = *reinterpret_cast<const bf16x4*>(Vtt + hi * 256 + lq * 4 + 128);
    const bf16x8 vt8 = vt8u.w;
#endif
    #pragma unroll
    for (int hf = 0; hf < 2; ++hf) {
      const bf16x8 q0 = hf ? qB0 : qA0;
      const bf16x8 q1 = hf ? qB1 : qA1;
      f32x16 s = __builtin_amdgcn_mfma_f32_32x32x16_bf16(kf0, q0, z, 0, 0, 0);
      s = __builtin_amdgcn_mfma_f32_32x32x16_bf16(kf1, q1, s, 0, 0, 0);
      float p_[8];
      #pragma unroll
      for (int r = 0; r < 8; ++r) p_[r] = __builtin_amdgcn_exp2f(s[r]);
      const float s01 = (p_[0] + p_[1]) + (p_[2] + p_[3]);
      const float s23 = (p_[4] + p_[5]) + (p_[6] + p_[7]);
      if (hf) { lb0 += s01; lb1 += s23; } else { la0 += s01; la1 += s23; }
#if HAS_PV8
      union UU { unsigned u[2]; bf16x4 v; };
      UU a0, a1;
      a0.u[0] = pk2(p_[0], p_[1]); a0.u[1] = pk2(p_[2], p_[3]);
      a1.u[0] = pk2(p_[4], p_[5]); a1.u[1] = pk2(p_[6], p_[7]);
      if (hf) {
        accB = __builtin_amdgcn_mfma_f32_32x32x8bf16_1k(a0.v, vt0, accB, 0, 0, 0);
        accB = __builtin_amdgcn_mfma_f32_32x32x8bf16_1k(a1.v, vt1, accB, 0, 0, 0);
      } else {
        accA = __builtin_amdgcn_mfma_f32_32x32x8bf16_1k(a0.v, vt0, accA, 0, 0, 0);
        accA = __builtin_amdgcn_mfma_f32_32x32x8bf16_1k(a1.v, vt1, accA, 0, 0, 0);
      }
#else
      unsigned a0u0 = pk2(p_[0], p_[1]), a0u1 = pk2(p_[2], p_[3]);
      unsigned a1u0 = pk2(p_[4], p_[5]), a1u1 = pk2(p_[6], p_[7]);
      union U8 { unsigned u[4]; bf16x8 v; };
      const unsigned s0 = __shfl_xor(hi ? a0u0 : a1u0, 32, 64);
      const unsigned s1 = __shfl_xor(hi ? a0u1 : a1u1, 32, 64);
      U8 f;
      f.u[0] = hi ? s0 : a0u0; f.u[1] = hi ? s1 : a0u1;
      f.u[2] = hi ? a1u0 : s0; f.u[3] = hi ? a1u1 : s1;
      if (hf) accB = __builtin_amdgcn_mfma_f32_32x32x16_bf16(f.v, vt8, accB, 0, 0, 0);
      else    accA = __builtin_amdgcn_mfma_f32_32x32x16_bf16(f.v, vt8, accA, 0, 0, 0);
#endif
    }
  }

  // write partials: P[sl][bh][q][d] (bf16, d = lq), L[sl][bh][q], both q-halves
  __hip_bfloat16* PpA = Pb + (((size_t)sl * 16 + bh) * NQ + qbase) * 32;
  #pragma unroll
  for (int r = 0; r < 16; ++r) {
    const int q = (r & 3) + 8 * (r >> 2) + 4 * hi;
    PpA[(size_t)q * 32 + lq] = __float2bfloat16(accA[r]);
    PpA[(size_t)(q + 32) * 32 + lq] = __float2bfloat16(accB[r]);
  }
  float lsA = (la0 + la1) + (la2 + la3);
  float lsB = (lb0 + lb1) + (lb2 + lb3);
  lsA += __shfl_xor(lsA, 32, 64);
  lsB += __shfl_xor(lsB, 32, 64);
  if (hi == 0) {
    Lb[((size_t)sl * 16 + bh) * NQ + qbase + lq] = lsA;
    Lb[((size_t)sl * 16 + bh) * NQ + qbase + 32 + lq] = lsB;
  }
}

// ---------------- Kernel 2b: combine split-K partials ----------------
// att[bh][q][d] = (sum_s P[s][bh][q][d]) / (sum_s L[s][bh][q])   (bf16)
// grid 2048 x 256: XCD-pinned; P bf16 -> 2.1 MB/XCD, L2-resident.
__global__ __launch_bounds__(256) void k2b_combine(
    const __hip_bfloat16* __restrict__ Pb, const float* __restrict__ Lb,
    __hip_bfloat16* __restrict__ att) {
  constexpr size_t PS = (size_t)16 * NQ * 32;       // per-slice P elements
  constexpr size_t LS = (size_t)16 * NQ;            // per-slice L elements
  const int wg  = blockIdx.x;          // 0..2047
  const int xcd = wg & 7;
  const int i   = wg >> 3;             // 0..255
  const int bh  = 2 * xcd + (i & 1);   // matches k2's bh->XCD pinning
  const int j   = i >> 1;              // 0..127
  const int u   = j * 256 + threadIdx.x;   // 0..32767 per bh
  const int q   = u >> 3;
  const int d0  = (u & 7) * 4;
  const size_t qi = (size_t)bh * NQ + q;

  float l = 0.f;
  #pragma unroll
  for (int s = 0; s < NSL; ++s) l += Lb[s * LS + qi];
  const float inv = 1.f / l;

  float4 o = make_float4(0.f, 0.f, 0.f, 0.f);
  #pragma unroll
  for (int s = 0; s < NSL; ++s) {
    const u16x4 f = *reinterpret_cast<const u16x4*>(Pb + s * PS + qi * 32 + d0);
    o.x += b2f(f[0]); o.y += b2f(f[1]); o.z += b2f(f[2]); o.w += b2f(f[3]);
  }
  *reinterpret_cast<uint2*>(att + qi * 32 + d0) =
      make_uint2(pk2(o.x * inv, o.y * inv), pk2(o.z * inv, o.w * inv));
}

// ---------------- Kernel 3: output projection ----------------
// grid (128 n-tiles, 4 batches), block 256 (4 waves, 2 o-tiles each).
// att layout is (bh, q, d): head k, d-range 8g..8g+7 for row n.
__global__ __launch_bounds__(256) void k3_proj(
    const __hip_bfloat16* __restrict__ att, const __hip_bfloat16* __restrict__ Wb,
    const float* __restrict__ bout, float* __restrict__ out) {
  const int b = blockIdx.y, nb = blockIdx.x * 32;
  const int wv = threadIdx.x >> 6, lane = threadIdx.x & 63;
  const int li = lane & 15, g = lane >> 4;

  bf16x8 wf[2][4];
  float bo[2][4];
  #pragma unroll
  for (int tt = 0; tt < 2; ++tt) {
    const int ot = 2 * wv + tt;
    #pragma unroll
    for (int k = 0; k < 4; ++k)
      wf[tt][k] = *reinterpret_cast<const bf16x8*>(
          &Wb[(size_t)(ot * 16 + li) * CDIM + k * 32 + 8 * g]);
    #pragma unroll
    for (int r = 0; r < 4; ++r) bo[tt][r] = bout[ot * 16 + 4 * g + r];
  }
  #pragma unroll
  for (int nt = 0; nt < 2; ++nt) {
    bf16x8 bfr[4];
    #pragma unroll
    for (int k = 0; k < 4; ++k)
      bfr[k] = *reinterpret_cast<const bf16x8*>(
          &att[(((size_t)(b * 4 + k)) * NQ + nb + nt * 16 + li) * 32 + 8 * g]);
    #pragma unroll
    for (int tt = 0; tt < 2; ++tt) {
      f32x4 a; a[0] = a[1] = a[2] = a[3] = 0.f;
      #pragma unroll
      for (int k = 0; k < 4; ++k)
        a = __builtin_amdgcn_mfma_f32_16x16x32_bf16(wf[tt][k], bfr[k], a, 0, 0, 0);
      const int ot = 2 * wv + tt;
      #pragma unroll
      for (int r = 0; r < 4; ++r)
        out[((size_t)b * CDIM + ot * 16 + 4 * g + r) * NQ + nb + nt * 16 + li] =
            a[r] + bo[tt][r];
    }
  }
}

extern "C" void kernel_launch(void* const* d_in, const int* in_sizes, int n_in,
                              void* d_out, int out_size, void* d_ws, size_t ws_size,
                              hipStream_t stream) {
  const float* x    = (const float*)d_in[0];
  const float* memp = (const float*)d_in[1];
  const float* wqkv = (const float*)d_in[2];
  const float* wout = (const float*)d_in[3];
  const float* bout = (const float*)d_in[4];
  float* out = (float*)d_out;

  char* ws = (char*)d_ws;
  const size_t SZ  = (size_t)16 * NP * 32 * 2;              // Qt/Kt each
  const size_t VSZ = (size_t)16 * 65 * VTILE * 2;           // Vt (tile image)
  const size_t PSZ = (size_t)NSL * 16 * NQ * 32 * 2;        // 16.8 MB (bf16)
  const size_t LSZ = (size_t)NSL * 16 * NQ * 4;             // 1 MB
  const size_t ASZ = (size_t)16 * NQ * 32 * 2;              // att (bh,q,d) bf16
  __hip_bfloat16* Qt  = (__hip_bfloat16*)(ws);
  __hip_bfloat16* Kt  = (__hip_bfloat16*)(ws + SZ);
  __hip_bfloat16* Vt  = (__hip_bfloat16*)(ws + 2 * SZ);
  __hip_bfloat16* Pbf = (__hip_bfloat16*)(ws + 2 * SZ + VSZ);
  float*          Lbf = (float*)(ws + 2 * SZ + VSZ + PSZ);
  __hip_bfloat16* att = (__hip_bfloat16*)(ws + 2 * SZ + VSZ + PSZ + LSZ);
  __hip_bfloat16* Wb  = (__hip_bfloat16*)(ws + 2 * SZ + VSZ + PSZ + LSZ + ASZ);

  hipLaunchKernelGGL(k1_qkv, dim3(65, 4, 2), dim3(256), 0, stream,
                     x, memp, wqkv, wout, Qt, Kt, Vt, Wb);
  hipLaunchKernelGGL(k2_attn, dim3(1024), dim3(256), 0, stream,
                     Qt, Kt, Vt, Pbf, Lbf);
  hipLaunchKernelGGL(k2b_combine, dim3(2048), dim3(256), 0, stream, Pbf, Lbf, att);
  hipLaunchKernelGGL(k3_proj, dim3(128, 4), dim3(256), 0, stream, att, Wb, bout, out);
}

// Round 15
// 89.104 us; speedup vs baseline: 1.0705x; 1.0014x over previous
//
#include <hip/hip_runtime.h>
#include <hip/hip_bf16.h>

// Problem constants
constexpr int NQ   = 4096;   // spatial tokens (H*W)
constexpr int NKV  = 4112;   // spatial + 16 memory tokens
constexpr int NP   = 4160;   // padded rows (65 * 64), pad is zeroed
constexpr int CDIM = 128;
constexpr int NSL  = 4;      // split-K slices (1024 keys each; slice 3 + tail)
constexpr int VTILE = 2048;  // V tile: 64 keys x 32 d (elements)
constexpr float QSC = 0.17677669529663687f * 1.4426950408889634f; // DH^-0.5 * log2(e)

typedef __attribute__((ext_vector_type(8)))  short bf16x8;
typedef __attribute__((ext_vector_type(4)))  short bf16x4;
typedef __attribute__((ext_vector_type(4)))  unsigned short u16x4;
typedef __attribute__((ext_vector_type(4)))  float f32x4;
typedef __attribute__((ext_vector_type(16))) float f32x16;

static __device__ __forceinline__ unsigned short bfbits(float f) {
  __hip_bfloat16 h = __float2bfloat16(f);
  return *reinterpret_cast<unsigned short*>(&h);
}
static __device__ __forceinline__ unsigned pk2(float a, float b) {
  return (unsigned)bfbits(a) | ((unsigned)bfbits(b) << 16);
}
static __device__ __forceinline__ float b2f(unsigned short u) {
  unsigned x = (unsigned)u << 16;
  return *reinterpret_cast<float*>(&x);
}

// async global->LDS, 16B per lane; LDS dest = wave-uniform base + lane*16
#define GLOAD_LDS16(gsrc, ldst)                                               \
  __builtin_amdgcn_global_load_lds(                                           \
      (const __attribute__((address_space(1))) unsigned int*)(gsrc),          \
      (__attribute__((address_space(3))) unsigned int*)(ldst), 16, 0, 0)

// ---------------- Kernel 1: QKV projection (+ w_out cast) ----------------
// grid (65, 4 batches, 2 o-halves), block 256 (4 waves, 3 o-tiles each).
//   Qt[bh][n][d] (bf16, pre-scaled by QSC), Kt[bh][n][d],
//   Vt: per-64-key-tile fragment image (matches k2's LDS layout exactly):
//     elem(d, n) = bh*65*VTILE + (n>>6)*VTILE + ((n>>5)&1)*1024
//                + ((n>>3)&3)*256 + ((n>>2)&1)*128 + d*4 + (n&3)
__global__ __launch_bounds__(256) void k1_qkv(
    const float* __restrict__ x, const float* __restrict__ memry,
    const float* __restrict__ wqkv, const float* __restrict__ wout,
    __hip_bfloat16* __restrict__ Qt, __hip_bfloat16* __restrict__ Kt,
    __hip_bfloat16* __restrict__ Vt, __hip_bfloat16* __restrict__ Wb) {
  __shared__ __align__(16) __hip_bfloat16 xt[64][136];  // [n-local][c], +8 pad
  const int b  = blockIdx.y;
  const int zz = blockIdx.z;                   // o-half: 0 -> tiles 0-11, 1 -> 12-23
  const int nb = blockIdx.x * 64;
  const int t  = threadIdx.x;
  const int wv = t >> 6, ln = t & 63;

  if (blockIdx.x == 0 && b == 0 && zz == 0) {
    for (int i = t; i < CDIM * CDIM; i += 256) Wb[i] = __float2bfloat16(wout[i]);
  }

  { // stage x_ext tile (transposed, bf16)
    const int n = nb + ln;
    #pragma unroll
    for (int i = 0; i < 16; ++i) {
      const int c = wv * 32 + 2 * i;
      float v0 = 0.f, v1 = 0.f;
      if (n < NQ)        { v0 = x[((size_t)b * CDIM + c) * NQ + n];
                           v1 = x[((size_t)b * CDIM + c + 1) * NQ + n]; }
      else if (n < NKV)  { v0 = memry[c * 16 + (n - NQ)];
                           v1 = memry[(c + 1) * 16 + (n - NQ)]; }
      *reinterpret_cast<unsigned*>(&xt[ln][c]) =
          (unsigned)bfbits(v0) | ((unsigned)bfbits(v1) << 16);
    }
  }
  __syncthreads();

  const int li = ln & 15, g = ln >> 4;
  bf16x8 xa[4][4];
  #pragma unroll
  for (int nt = 0; nt < 4; ++nt)
    #pragma unroll
    for (int k = 0; k < 4; ++k)
      xa[nt][k] = *reinterpret_cast<const bf16x8*>(&xt[nt * 16 + li][k * 32 + 8 * g]);

  #pragma unroll
  for (int oi = 0; oi < 3; ++oi) {
    const int ot = zz * 12 + wv * 3 + oi;       // 24 o-tiles: 0-7 Q, 8-15 K, 16-23 V
    bf16x8 wf[4];
    #pragma unroll
    for (int k = 0; k < 4; ++k) {
      const float* wp = &wqkv[(size_t)(ot * 16 + li) * CDIM + k * 32 + 8 * g];
      const float4 f0 = *reinterpret_cast<const float4*>(wp);
      const float4 f1 = *reinterpret_cast<const float4*>(wp + 4);
      bf16x8 wc;
      wc[0] = (short)bfbits(f0.x); wc[1] = (short)bfbits(f0.y);
      wc[2] = (short)bfbits(f0.z); wc[3] = (short)bfbits(f0.w);
      wc[4] = (short)bfbits(f1.x); wc[5] = (short)bfbits(f1.y);
      wc[6] = (short)bfbits(f1.z); wc[7] = (short)bfbits(f1.w);
      wf[k] = wc;
    }
    #pragma unroll
    for (int nt = 0; nt < 4; ++nt) {
      f32x4 a; a[0] = a[1] = a[2] = a[3] = 0.f;
      if (ot < 16) {
        // D[row=n][col=o]  (A = x-tile, B = W^T)
        #pragma unroll
        for (int k = 0; k < 4; ++k)
          a = __builtin_amdgcn_mfma_f32_16x16x32_bf16(xa[nt][k], wf[k], a, 0, 0, 0);
        const int o = ot * 16 + li;
        const int h = (o >> 5) & 3, d = o & 31;
        if (ot < 8) {
          #pragma unroll
          for (int r = 0; r < 4; ++r) {
            const int n = nb + nt * 16 + 4 * g + r;
            Qt[((size_t)(b * 4 + h) * NP + n) * 32 + d] = __float2bfloat16(a[r] * QSC);
          }
        } else {
          #pragma unroll
          for (int r = 0; r < 4; ++r) {
            const int n = nb + nt * 16 + 4 * g + r;
            Kt[((size_t)(b * 4 + h) * NP + n) * 32 + d] = __float2bfloat16(a[r]);
          }
        }
      } else {
        // D[row=o][col=n]  (A = W, B = x-tile); V in tile-fragment order
        #pragma unroll
        for (int k = 0; k < 4; ++k)
          a = __builtin_amdgcn_mfma_f32_16x16x32_bf16(wf[k], xa[nt][k], a, 0, 0, 0);
        const int n = nb + nt * 16 + li;
        const size_t vb = (size_t)(b * 4) * 65 * VTILE       // h added below
                        + (size_t)(n >> 6) * VTILE + ((n >> 5) & 1) * 1024
                        + ((n >> 3) & 3) * 256 + ((n >> 2) & 1) * 128 + (n & 3);
        #pragma unroll
        for (int r = 0; r < 4; ++r) {
          const int o = ot * 16 + 4 * g + r;
          const int h = (o >> 5) & 3, d = o & 31;
          Vt[vb + (size_t)h * 65 * VTILE + d * 4] = __float2bfloat16(a[r]);
        }
      }
    }
  }
}

// ---- Kernel 2: attention partials; global_load_lds staging (round-13 body) ----
// L reverted to f32 VALU sums (round 14's ones-MFMA bf16-L broke tolerance).
// grid 1024 flat blocks (XCD-pinned), block 256 = 4 waves, 64 q per wave.

#if __has_builtin(__builtin_amdgcn_mfma_f32_32x32x8bf16_1k)
#define HAS_PV8 1
#else
#define HAS_PV8 0
#endif

#if HAS_PV8
__device__ __forceinline__ void half32(
    const bf16x8& kf0, const bf16x8& kf1,
    const bf16x4& vf0, const bf16x4& vf1, const bf16x4& vf2, const bf16x4& vf3,
    const bf16x8& q0, const bf16x8& q1, const f32x16& z,
    f32x16& acc, float& l0, float& l1, float& l2, float& l3) {
  f32x16 s = __builtin_amdgcn_mfma_f32_32x32x16_bf16(kf0, q0, z, 0, 0, 0);
  s = __builtin_amdgcn_mfma_f32_32x32x16_bf16(kf1, q1, s, 0, 0, 0);
  float p[16];
  #pragma unroll
  for (int r = 0; r < 16; ++r) p[r] = __builtin_amdgcn_exp2f(s[r]);
  l0 += (p[0] + p[1]) + (p[2] + p[3]);
  l1 += (p[4] + p[5]) + (p[6] + p[7]);
  l2 += (p[8] + p[9]) + (p[10] + p[11]);
  l3 += (p[12] + p[13]) + (p[14] + p[15]);
  union UU { unsigned u[2]; bf16x4 v; };
  UU a0, a1, a2, a3;  // quad r -> keys {0,8,16,24} + 4*hi + 0..3
  a0.u[0] = pk2(p[0], p[1]);   a0.u[1] = pk2(p[2], p[3]);
  a1.u[0] = pk2(p[4], p[5]);   a1.u[1] = pk2(p[6], p[7]);
  a2.u[0] = pk2(p[8], p[9]);   a2.u[1] = pk2(p[10], p[11]);
  a3.u[0] = pk2(p[12], p[13]); a3.u[1] = pk2(p[14], p[15]);
  acc = __builtin_amdgcn_mfma_f32_32x32x8bf16_1k(a0.v, vf0, acc, 0, 0, 0);
  acc = __builtin_amdgcn_mfma_f32_32x32x8bf16_1k(a1.v, vf1, acc, 0, 0, 0);
  acc = __builtin_amdgcn_mfma_f32_32x32x8bf16_1k(a2.v, vf2, acc, 0, 0, 0);
  acc = __builtin_amdgcn_mfma_f32_32x32x8bf16_1k(a3.v, vf3, acc, 0, 0, 0);
}
#else
__device__ __forceinline__ void half32_fb(
    const bf16x8& kf0, const bf16x8& kf1,
    const bf16x8& vh0, const bf16x8& vh1, int hi,
    const bf16x8& q0, const bf16x8& q1, const f32x16& z,
    f32x16& acc, float& l0, float& l1, float& l2, float& l3) {
  f32x16 s = __builtin_amdgcn_mfma_f32_32x32x16_bf16(kf0, q0, z, 0, 0, 0);
  s = __builtin_amdgcn_mfma_f32_32x32x16_bf16(kf1, q1, s, 0, 0, 0);
  float p[16];
  #pragma unroll
  for (int r = 0; r < 16; ++r) p[r] = __builtin_amdgcn_exp2f(s[r]);
  l0 += (p[0] + p[1]) + (p[2] + p[3]);
  l1 += (p[4] + p[5]) + (p[6] + p[7]);
  l2 += (p[8] + p[9]) + (p[10] + p[11]);
  l3 += (p[12] + p[13]) + (p[14] + p[15]);
  unsigned a0u0 = pk2(p[0], p[1]),   a0u1 = pk2(p[2], p[3]);
  unsigned a1u0 = pk2(p[4], p[5]),   a1u1 = pk2(p[6], p[7]);
  unsigned a2u0 = pk2(p[8], p[9]),   a2u1 = pk2(p[10], p[11]);
  unsigned a3u0 = pk2(p[12], p[13]), a3u1 = pk2(p[14], p[15]);
  union U8 { unsigned u[4]; bf16x8 v; };
  {
    const unsigned s0 = __shfl_xor(hi ? a0u0 : a1u0, 32, 64);
    const unsigned s1 = __shfl_xor(hi ? a0u1 : a1u1, 32, 64);
    U8 f;
    f.u[0] = hi ? s0 : a0u0; f.u[1] = hi ? s1 : a0u1;
    f.u[2] = hi ? a1u0 : s0; f.u[3] = hi ? a1u1 : s1;
    acc = __builtin_amdgcn_mfma_f32_32x32x16_bf16(f.v, vh0, acc, 0, 0, 0);
  }
  {
    const unsigned s0 = __shfl_xor(hi ? a2u0 : a3u0, 32, 64);
    const unsigned s1 = __shfl_xor(hi ? a2u1 : a3u1, 32, 64);
    U8 f;
    f.u[0] = hi ? s0 : a2u0; f.u[1] = hi ? s1 : a2u1;
    f.u[2] = hi ? a3u0 : s0; f.u[3] = hi ? a3u1 : s1;
    acc = __builtin_amdgcn_mfma_f32_32x32x16_bf16(f.v, vh1, acc, 0, 0, 0);
  }
}
#endif

__global__ __launch_bounds__(256, 3) void k2_attn(
    const __hip_bfloat16* __restrict__ Qt, const __hip_bfloat16* __restrict__ Kt,
    const __hip_bfloat16* __restrict__ Vt, __hip_bfloat16* __restrict__ Pb,
    float* __restrict__ Lb) {
  // two 8KB staging buffers: [K 4KB | V 4KB] each
  __shared__ __align__(16) unsigned char smem[16384];

  // XCD-pinned decomposition (assumes xcd = blockIdx % 8; perf-only heuristic)
  const int wg  = blockIdx.x;          // 0..1023
  const int xcd = wg & 7;
  const int i   = wg >> 3;             // 0..127
  const int bh  = 2 * xcd + (i & 1);   // 2 bh per XCD
  const int sl  = (i >> 1) & 3;        // split-K slice 0..3
  const int iq  = i >> 3;              // 0..15 -> 256-q block
  const int wv  = threadIdx.x >> 6, lane = threadIdx.x & 63;
  const int lq  = lane & 31, hi = lane >> 5;
  const int qbase = iq * 256 + wv * 64;   // this wave's 64 queries

  const bf16x8 qA0 = *reinterpret_cast<const bf16x8*>(
      Qt + ((size_t)bh * NP + qbase + lq) * 32 + 8 * hi);
  const bf16x8 qA1 = *reinterpret_cast<const bf16x8*>(
      Qt + ((size_t)bh * NP + qbase + lq) * 32 + 16 + 8 * hi);
  const bf16x8 qB0 = *reinterpret_cast<const bf16x8*>(
      Qt + ((size_t)bh * NP + qbase + 32 + lq) * 32 + 8 * hi);
  const bf16x8 qB1 = *reinterpret_cast<const bf16x8*>(
      Qt + ((size_t)bh * NP + qbase + 32 + lq) * 32 + 16 + 8 * hi);

  // staging sources: per-lane global addresses; tile stride = 2048 elements
  const int kb0 = sl * 1024;
  const __hip_bfloat16* Ksrc = Kt + ((size_t)bh * NP + kb0 + (wv >> 1) * 32 + lq) * 32
                                  + (wv & 1) * 16 + 8 * hi;
  const __hip_bfloat16* Vsrc = Vt + (size_t)bh * 65 * VTILE
                                  + (size_t)(kb0 >> 6) * VTILE + threadIdx.x * 8;
  // LDS dests: wave-uniform bases (HW adds lane*16)
  const int kofs = wv * 1024;          // within K region
  const int rdv  = hi * 256 + lq * 8;  // V read base (contiguous per op)

  f32x16 accA, accB, z;
  #pragma unroll
  for (int q = 0; q < 16; ++q) { accA[q] = 0.f; accB[q] = 0.f; z[q] = 0.f; }
  float la0 = 0.f, la1 = 0.f, la2 = 0.f, la3 = 0.f;
  float lb0 = 0.f, lb1 = 0.f, lb2 = 0.f, lb3 = 0.f;

  // prologue: tile 0 -> buf0 (DMA)
  GLOAD_LDS16(Ksrc, smem + kofs);
  GLOAD_LDS16(Vsrc, smem + 4096 + kofs);

  for (int t = 0; t < 16; ++t) {
    __syncthreads();   // drains outstanding global_load_lds into buf[t&1]
    const int p = t & 1;
    { // stage tile t+1 into the idle buffer (t=15 stages the valid pad tile)
      unsigned char* nbuf = smem + (p ^ 1) * 8192;
      GLOAD_LDS16(Ksrc + (size_t)(t + 1) * 2048, nbuf + kofs);
      GLOAD_LDS16(Vsrc + (size_t)(t + 1) * 2048, nbuf + 4096 + kofs);
    }
    const unsigned char* kbuf = smem + p * 8192;
    const unsigned char* vbase = kbuf + 4096;

    #pragma unroll
    for (int st = 0; st < 2; ++st) {           // two 32-key subtiles
      const bf16x8 kf0 = *reinterpret_cast<const bf16x8*>(kbuf + st * 2048 + lane * 16);
      const bf16x8 kf1 = *reinterpret_cast<const bf16x8*>(kbuf + st * 2048 + 1024 + lane * 16);
#if HAS_PV8
      const unsigned char* vb = vbase + st * 2048;
      const bf16x4 vf0 = *reinterpret_cast<const bf16x4*>(vb + rdv);
      const bf16x4 vf1 = *reinterpret_cast<const bf16x4*>(vb + 512 + rdv);
      const bf16x4 vf2 = *reinterpret_cast<const bf16x4*>(vb + 1024 + rdv);
      const bf16x4 vf3 = *reinterpret_cast<const bf16x4*>(vb + 1536 + rdv);
      half32(kf0, kf1, vf0, vf1, vf2, vf3, qA0, qA1, z, accA, la0, la1, la2, la3);
      half32(kf0, kf1, vf0, vf1, vf2, vf3, qB0, qB1, z, accB, lb0, lb1, lb2, lb3);
#else
      const unsigned char* vb = vbase + st * 2048;
      union { bf16x4 h[2]; bf16x8 w; } vh0, vh1;
      vh0.h[0] = *reinterpret_cast<const bf16x4*>(vb + hi * 512 + lq * 8);
      vh0.h[1] = *reinterpret_cast<const bf16x4*>(vb + hi * 512 + 256 + lq * 8);
      vh1.h[0] = *reinterpret_cast<const bf16x4*>(vb + (2 + hi) * 512 + lq * 8);
      vh1.h[1] = *reinterpret_cast<const bf16x4*>(vb + (2 + hi) * 512 + 256 + lq * 8);
      half32_fb(kf0, kf1, vh0.w, vh1.w, hi, qA0, qA1, z, accA, la0, la1, la2, la3);
      half32_fb(kf0, kf1, vh0.w, vh1.w, hi, qB0, qB1, z, accB, lb0, lb1, lb2, lb3);
#endif
    }
  }

  if (sl == NSL - 1) {
    // tail: 16 real keys (4096..4111), direct from global (L2-hot, tiny)
    const __hip_bfloat16* Kp = Kt + (size_t)bh * NP * 32 + (size_t)lq * 32 + 8 * hi;
    const __hip_bfloat16* Vtt = Vt + (size_t)bh * 65 * VTILE + (size_t)64 * VTILE;
    const int kb = 4096;
    const bf16x8 kf0 = *reinterpret_cast<const bf16x8*>(Kp + (size_t)kb * 32);
    const bf16x8 kf1 = *reinterpret_cast<const bf16x8*>(Kp + (size_t)kb * 32 + 16);
#if HAS_PV8
    // keys 4*hi+0..3 at hi*128+lq*4 elems; keys 8+4*hi at +256 elems
    const bf16x4 vt0 = *reinterpret_cast<const bf16x4*>(Vtt + hi * 128 + lq * 4);
    const bf16x4 vt1 = *reinterpret_cast<const bf16x4*>(Vtt + 256 + hi * 128 + lq * 4);
#else
    union { bf16x4 h[2]; bf16x8 w; } vt8u;
    vt8u.h[0] = *reinterpret_cast<const bf16x4*>(Vtt + hi * 256 + lq * 4 + 0);
    vt8u.h[1] = *reinterpret_cast<const bf16x4*>(Vtt + hi * 256 + lq * 4 + 128);
    const bf16x8 vt8 = vt8u.w;
#endif
    #pragma unroll
    for (int hf = 0; hf < 2; ++hf) {
      const bf16x8 q0 = hf ? qB0 : qA0;
      const bf16x8 q1 = hf ? qB1 : qA1;
      f32x16 s = __builtin_amdgcn_mfma_f32_32x32x16_bf16(kf0, q0, z, 0, 0, 0);
      s = __builtin_amdgcn_mfma_f32_32x32x16_bf16(kf1, q1, s, 0, 0, 0);
      float p_[8];
      #pragma unroll
      for (int r = 0; r < 8; ++r) p_[r] = __builtin_amdgcn_exp2f(s[r]);
      const float s01 = (p_[0] + p_[1]) + (p_[2] + p_[3]);
      const float s23 = (p_[4] + p_[5]) + (p_[6] + p_[7]);
      if (hf) { lb0 += s01; lb1 += s23; } else { la0 += s01; la1 += s23; }
#if HAS_PV8
      union UU { unsigned u[2]; bf16x4 v; };
      UU a0, a1;
      a0.u[0] = pk2(p_[0], p_[1]); a0.u[1] = pk2(p_[2], p_[3]);
      a1.u[0] = pk2(p_[4], p_[5]); a1.u[1] = pk2(p_[6], p_[7]);
      if (hf) {
        accB = __builtin_amdgcn_mfma_f32_32x32x8bf16_1k(a0.v, vt0, accB, 0, 0, 0);
        accB = __builtin_amdgcn_mfma_f32_32x32x8bf16_1k(a1.v, vt1, accB, 0, 0, 0);
      } else {
        accA = __builtin_amdgcn_mfma_f32_32x32x8bf16_1k(a0.v, vt0, accA, 0, 0, 0);
        accA = __builtin_amdgcn_mfma_f32_32x32x8bf16_1k(a1.v, vt1, accA, 0, 0, 0);
      }
#else
      unsigned a0u0 = pk2(p_[0], p_[1]), a0u1 = pk2(p_[2], p_[3]);
      unsigned a1u0 = pk2(p_[4], p_[5]), a1u1 = pk2(p_[6], p_[7]);
      union U8 { unsigned u[4]; bf16x8 v; };
      const unsigned s0 = __shfl_xor(hi ? a0u0 : a1u0, 32, 64);
      const unsigned s1 = __shfl_xor(hi ? a0u1 : a1u1, 32, 64);
      U8 f;
      f.u[0] = hi ? s0 : a0u0; f.u[1] = hi ? s1 : a0u1;
      f.u[2] = hi ? a1u0 : s0; f.u[3] = hi ? a1u1 : s1;
      if (hf) accB = __builtin_amdgcn_mfma_f32_32x32x16_bf16(f.v, vt8, accB, 0, 0, 0);
      else    accA = __builtin_amdgcn_mfma_f32_32x32x16_bf16(f.v, vt8, accA, 0, 0, 0);
#endif
    }
  }

  // write partials: P[sl][bh][q][d] (bf16, d = lq), L[sl][bh][q], both q-halves
  __hip_bfloat16* PpA = Pb + (((size_t)sl * 16 + bh) * NQ + qbase) * 32;
  #pragma unroll
  for (int r = 0; r < 16; ++r) {
    const int q = (r & 3) + 8 * (r >> 2) + 4 * hi;
    PpA[(size_t)q * 32 + lq] = __float2bfloat16(accA[r]);
    PpA[(size_t)(q + 32) * 32 + lq] = __float2bfloat16(accB[r]);
  }
  float lsA = (la0 + la1) + (la2 + la3);
  float lsB = (lb0 + lb1) + (lb2 + lb3);
  lsA += __shfl_xor(lsA, 32, 64);
  lsB += __shfl_xor(lsB, 32, 64);
  if (hi == 0) {
    Lb[((size_t)sl * 16 + bh) * NQ + qbase + lq] = lsA;
    Lb[((size_t)sl * 16 + bh) * NQ + qbase + 32 + lq] = lsB;
  }
}

// ------- Kernel 3: output projection, fused split-K combine -------
// grid (256 n-tiles, 4 batches), block 256 (4 waves, 2 o-tiles each, 16 n).
// Fragments built from bf16 P slices: (sum_s P_s) * inv, inv = 1/(sum_s L_s).
// Identical arithmetic to round 13's k2b followed by k3.
__global__ __launch_bounds__(256) void k3_proj(
    const __hip_bfloat16* __restrict__ Pb, const float* __restrict__ Lb,
    const __hip_bfloat16* __restrict__ Wb, const float* __restrict__ bout,
    float* __restrict__ out) {
  constexpr size_t PS = (size_t)16 * NQ * 32;
  constexpr size_t LS = (size_t)16 * NQ;
  const int b = blockIdx.y, nb = blockIdx.x * 16;
  const int wv = threadIdx.x >> 6, lane = threadIdx.x & 63;
  const int li = lane & 15, g = lane >> 4;

  bf16x8 wf[2][4];
  float bo[2][4];
  #pragma unroll
  for (int tt = 0; tt < 2; ++tt) {
    const int ot = 2 * wv + tt;
    #pragma unroll
    for (int k = 0; k < 4; ++k)
      wf[tt][k] = *reinterpret_cast<const bf16x8*>(
          &Wb[(size_t)(ot * 16 + li) * CDIM + k * 32 + 8 * g]);
    #pragma unroll
    for (int r = 0; r < 4; ++r) bo[tt][r] = bout[ot * 16 + 4 * g + r];
  }

  const int q = nb + li;
  bf16x8 bfr[4];
  #pragma unroll
  for (int k = 0; k < 4; ++k) {
    const size_t qi = (size_t)(b * 4 + k) * NQ + q;
    const float inv = 1.f / (((Lb[qi] + Lb[LS + qi]) +
                              (Lb[2 * LS + qi] + Lb[3 * LS + qi])));
    const __hip_bfloat16* pp = Pb + qi * 32 + 8 * g;
    float e[8];
    #pragma unroll
    for (int j = 0; j < 8; ++j) e[j] = 0.f;
    #pragma unroll
    for (int s = 0; s < NSL; ++s) {
      const u16x4 f0 = *reinterpret_cast<const u16x4*>(pp + s * PS);
      const u16x4 f1 = *reinterpret_cast<const u16x4*>(pp + s * PS + 4);
      e[0] += b2f(f0[0]); e[1] += b2f(f0[1]); e[2] += b2f(f0[2]); e[3] += b2f(f0[3]);
      e[4] += b2f(f1[0]); e[5] += b2f(f1[1]); e[6] += b2f(f1[2]); e[7] += b2f(f1[3]);
    }
    bf16x8 fr;
    #pragma unroll
    for (int j = 0; j < 8; ++j) fr[j] = (short)bfbits(e[j] * inv);
    bfr[k] = fr;
  }

  #pragma unroll
  for (int tt = 0; tt < 2; ++tt) {
    f32x4 a; a[0] = a[1] = a[2] = a[3] = 0.f;
    #pragma unroll
    for (int k = 0; k < 4; ++k)
      a = __builtin_amdgcn_mfma_f32_16x16x32_bf16(wf[tt][k], bfr[k], a, 0, 0, 0);
    const int ot = 2 * wv + tt;
    #pragma unroll
    for (int r = 0; r < 4; ++r)
      out[((size_t)b * CDIM + ot * 16 + 4 * g + r) * NQ + q] = a[r] + bo[tt][r];
  }
}

extern "C" void kernel_launch(void* const* d_in, const int* in_sizes, int n_in,
                              void* d_out, int out_size, void* d_ws, size_t ws_size,
                              hipStream_t stream) {
  const float* x    = (const float*)d_in[0];
  const float* memp = (const float*)d_in[1];
  const float* wqkv = (const float*)d_in[2];
  const float* wout = (const float*)d_in[3];
  const float* bout = (const float*)d_in[4];
  float* out = (float*)d_out;

  char* ws = (char*)d_ws;
  const size_t SZ  = (size_t)16 * NP * 32 * 2;              // Qt/Kt each
  const size_t VSZ = (size_t)16 * 65 * VTILE * 2;           // Vt (tile image)
  const size_t PSZ = (size_t)NSL * 16 * NQ * 32 * 2;        // 16.8 MB (bf16)
  const size_t LSZ = (size_t)NSL * 16 * NQ * 4;             // 1 MB
  __hip_bfloat16* Qt  = (__hip_bfloat16*)(ws);
  __hip_bfloat16* Kt  = (__hip_bfloat16*)(ws + SZ);
  __hip_bfloat16* Vt  = (__hip_bfloat16*)(ws + 2 * SZ);
  __hip_bfloat16* Pbf = (__hip_bfloat16*)(ws + 2 * SZ + VSZ);
  float*          Lbf = (float*)(ws + 2 * SZ + VSZ + PSZ);
  __hip_bfloat16* Wb  = (__hip_bfloat16*)(ws + 2 * SZ + VSZ + PSZ + LSZ);

  hipLaunchKernelGGL(k1_qkv, dim3(65, 4, 2), dim3(256), 0, stream,
                     x, memp, wqkv, wout, Qt, Kt, Vt, Wb);
  hipLaunchKernelGGL(k2_attn, dim3(1024), dim3(256), 0, stream,
                     Qt, Kt, Vt, Pbf, Lbf);
  hipLaunchKernelGGL(k3_proj, dim3(256, 4), dim3(256), 0, stream,
                     Pbf, Lbf, Wb, bout, out);
}